// Round 11
// baseline (4532.940 us; speedup 1.0000x reference)
//
#include <hip/hip_runtime.h>
#include <hip/hip_bf16.h>

// ============================================================================
// GRU seq2seq (3-layer enc + 3-cell dec + linear), B=2048, H=60, F=1, fp32.
//
// Round 11: ONE WAVE PER LAYER (3 waves/block, 128 blocks x 16 rows).
//  - Each wave computes ALL 192 gate cols for its 16 batch rows (12 MFMA
//    tiles). The h_{t-1} -> A-operand dependency is now WITHIN-wave (write
//    LDS, read back next slot) -- no sibling all-to-all. Only cross-wave
//    edge: g-1 -> g handoff, one 3-wave barrier per slot.
//    r10 proved slot ~ per-wave serial path; r2..r10 proved the 4-wave
//    exchange + 12-wave convoy costs ~1400cy/slot. This removes it.
//  - Weights VGPR-resident: Whh hi+lo (192 regs) + Wx hi (96; g0 scalar path
//    instead). __launch_bounds__(192,1) -> 512-reg budget, est ~420 used.
//  - f16 single-plane ring (r9-verified); fp32 h in regs; decoder y inline
//    on g2 (C-layout h) via 16-lane shfl_xor reduce, lin_w as scalars.
//  - Kept: prep frag format (verified), lgkmcnt-only barrier, x prefetch.
// ============================================================================

typedef float    f32x4 __attribute__((ext_vector_type(4)));
typedef _Float16 f16x8 __attribute__((ext_vector_type(8)));

#define RSTR 72               // ring row stride in shorts
#define REG  (16 * RSTR)      // shorts per region

struct CellB  { const float* bih; const float* bhh; const float* wih_vec; };
struct PhaseArgs {
  const float* xseq;          // [2048][512] fp32
  const unsigned short* frags;
  CellB cell[3];
  const float* hfin_rd;       // dec: [3][2048][64] fp32
  float* hfin_wr;             // enc
  const float* lin_w;         // [60]
  const float* lin_b;         // [1]
  float* y;                   // [2048][512]
};
struct PrepArgs {
  const float* w[13];         // (wih,whh) x 6 cells, then lin_w
  int din[13];
  unsigned short* out;
};

union HU { _Float16 h; unsigned short u; };
__device__ __forceinline__ unsigned short f2h(float x) { HU c; c.h = (_Float16)x; return c.u; }
__device__ __forceinline__ float h2f(unsigned short s) { HU c; c.u = s; return (float)c.h; }
__device__ __forceinline__ void wg_barrier() {
  asm volatile("s_waitcnt lgkmcnt(0)" ::: "memory");
  __builtin_amdgcn_s_barrier();
}

// ---------------------------------------------------------------------------
// Prep: f16 B-fragments (hi = f16(v), lo = f16(v - float(hi))) for 6 cells x
// {wih,whh} (cm 0..11); cm 12 unused by the phase kernel (kept for layout).
// frag_idx = (cm*12+tile)*4 + s2*2 + sp; short off = frag_idx*512 + lane*8 + e.
// element: col c = tile*16+(lane&15); k = s2*32+(lane>>4)*8+e.
// ---------------------------------------------------------------------------
__global__ void prep_frags(PrepArgs P) {
  int id = blockIdx.x * 256 + threadIdx.x;       // 1248*256 = 319488
  int e    = id & 7;
  int lane = (id >> 3) & 63;
  int sp   = (id >> 9) & 1;
  int s2   = (id >> 10) & 1;
  int rest = id >> 11;
  int tile = rest % 12;
  int cm   = rest / 12;
  if (cm > 12) return;
  const float* W = P.w[cm];
  int din = P.din[cm];
  int c = tile * 16 + (lane & 15);
  int k = s2 * 32 + (lane >> 4) * 8 + e;
  float v = 0.f;
  if (cm == 12) {
    if (c == 0 && k < 60) v = W[k];
  } else {
    int j = c & 63, sec = c >> 6;
    if (j < 60 && k < din) v = W[(sec * 60 + j) * din + k];
  }
  unsigned short hi = f2h(v);
  unsigned short o = sp ? f2h(v - h2f(hi)) : hi;
  P.out[id] = o;
}

// h-path: A x (Whi + Wlo), two independent 2-deep chains (4 MFMA)
__device__ __forceinline__ f32x4 mmh(f32x4 acc, const f16x8 A0, const f16x8 A1,
                                     const f16x8 B[2][2]) {
  f32x4 a2 = {0.f, 0.f, 0.f, 0.f};
  acc = __builtin_amdgcn_mfma_f32_16x16x32_f16(A0, B[0][0], acc, 0, 0, 0);
  a2  = __builtin_amdgcn_mfma_f32_16x16x32_f16(A0, B[0][1], a2,  0, 0, 0);
  acc = __builtin_amdgcn_mfma_f32_16x16x32_f16(A1, B[1][0], acc, 0, 0, 0);
  a2  = __builtin_amdgcn_mfma_f32_16x16x32_f16(A1, B[1][1], a2,  0, 0, 0);
  return acc + a2;
}
// x-path: A x Whi only (2 MFMA, one chain)
__device__ __forceinline__ f32x4 mmx(f32x4 acc, const f16x8 A0, const f16x8 A1,
                                     const f16x8 B[2]) {
  acc = __builtin_amdgcn_mfma_f32_16x16x32_f16(A0, B[0], acc, 0, 0, 0);
  acc = __builtin_amdgcn_mfma_f32_16x16x32_f16(A1, B[1], acc, 0, 0, 0);
  return acc;
}

// ---------------------------------------------------------------------------
// Fused 3-stage GRU pipeline, 1 wave per layer (3 waves/block).
// Ring: [region 0..5][row 0..15][col 0..63 of RSTR] f16; region = g*2+parity.
// Wave g owns all 192 gate cols x 16 rows of layer/cell g.
// ---------------------------------------------------------------------------
template <int IS_DEC>
__global__ __launch_bounds__(192, 1) void gru_phase(PhaseArgs P) {
  __shared__ alignas(16) unsigned short ring[6 * REG];

  const int tid  = threadIdx.x;
  const int lane = tid & 63;
  const int g    = tid >> 6;      // layer/cell 0..2 (one wave each)
  const int c16  = lane & 15;
  const int q16  = lane >> 4;
  const int row_base = blockIdx.x * 16;
  const int cell = (IS_DEC ? 3 : 0) + g;
  const bool din1 = (g == 0);
  const bool yd   = (IS_DEC && g == 2);

  // per-lane LDS offsets (shorts)
  int woq[4];
#pragma unroll
  for (int q = 0; q < 4; ++q) woq[q] = (4 * q16 + q) * RSTR + c16;
  const int ro0 = c16 * RSTR + q16 * 8;
  const int ro1 = ro0 + 32;

  // per-lane constants (per col-tile Th: col c = c16 + 16*Th)
  const float* bih = P.cell[g].bih;
  const float* bhh = P.cell[g].bhh;
  float b_r[4], b_z[4], b_hn[4], b_in[4];
  float w_r[4], w_z[4], w_n[4], lwv[4];
#pragma unroll
  for (int Th = 0; Th < 4; ++Th) {
    const int c = c16 + 16 * Th;
    const bool cv = (c < 60);
    b_r[Th]  = cv ? bih[c] + bhh[c]           : 0.f;
    b_z[Th]  = cv ? bih[60 + c] + bhh[60 + c] : 0.f;
    b_hn[Th] = cv ? bhh[120 + c]              : 0.f;
    b_in[Th] = cv ? bih[120 + c]              : 0.f;
    w_r[Th] = w_z[Th] = w_n[Th] = 0.f;
    if (din1 && cv) {
      const float* wv = P.cell[g].wih_vec;
      w_r[Th] = wv[c]; w_z[Th] = wv[60 + c]; w_n[Th] = wv[120 + c];
    }
    lwv[Th] = (yd && cv) ? P.lin_w[c] : 0.f;
  }
  const float lb = IS_DEC ? P.lin_b[0] : 0.f;

  // persistent weight fragments: all 12 tiles. Whh hi+lo; Wx hi (g>0 only).
  f16x8 Bh[12][2][2];
#pragma unroll
  for (int T = 0; T < 12; ++T)
#pragma unroll
    for (int s2 = 0; s2 < 2; ++s2)
#pragma unroll
      for (int sp = 0; sp < 2; ++sp)
        Bh[T][s2][sp] = *(const f16x8*)(P.frags +
            (size_t)(((cell * 2 + 1) * 12 + T) * 4 + s2 * 2 + sp) * 512 + lane * 8);
  f16x8 Bx[12][2];
  if (!din1) {
#pragma unroll
    for (int T = 0; T < 12; ++T)
#pragma unroll
      for (int s2 = 0; s2 < 2; ++s2)
        Bx[T][s2] = *(const f16x8*)(P.frags +
            (size_t)(((cell * 2 + 0) * 12 + T) * 4 + s2 * 2 + 0) * 512 + lane * 8);
  }

  // h0 (enc: zeros; dec: encoder final h) into parity-1 region (t=0 read slot)
  float hreg[4][4];
#pragma unroll
  for (int Th = 0; Th < 4; ++Th)
#pragma unroll
    for (int q = 0; q < 4; ++q) {
      float h0 = 0.f;
      if (IS_DEC)
        h0 = P.hfin_rd[((size_t)(2 - g) * 2048 + row_base + 4 * q16 + q) * 64 +
                       c16 + 16 * Th];
      hreg[Th][q] = h0;
      ring[(g * 2 + 1) * REG + woq[q] + 16 * Th] = f2h(h0);
    }

  // x prefetch (t=0) for g0
  float xcur[4] = {0.f, 0.f, 0.f, 0.f};
  if (din1) {
    const float* xp = P.xseq + (size_t)row_base * 512;
#pragma unroll
    for (int q = 0; q < 4; ++q) xcur[q] = xp[(size_t)(4 * q16 + q) * 512];
  }
  wg_barrier();

#pragma unroll 1
  for (int s = 0; s < 514; ++s) {
    const int t = s - g;
    if (t >= 0 && t < 512) {
      // ---- A loads: own h_{t-1} (written by THIS wave last slot) + x tile
      const int oR = (g * 2 + ((t + 1) & 1)) * REG;
      f16x8 A0 = *(const f16x8*)(ring + oR + ro0);
      f16x8 A1 = *(const f16x8*)(ring + oR + ro1);
      f16x8 X0, X1;
      if (!din1) {
        const int oX = ((g - 1) * 2 + (t & 1)) * REG;
        X0 = *(const f16x8*)(ring + oX + ro0);
        X1 = *(const f16x8*)(ring + oX + ro1);
      }

      // ---- gate pre-activations for all 12 tiles
      f32x4 aR[4], aZ[4], aHN[4], aIN[4];
#pragma unroll
      for (int Th = 0; Th < 4; ++Th) {
        aR[Th]  = (f32x4){b_r[Th],  b_r[Th],  b_r[Th],  b_r[Th]};
        aZ[Th]  = (f32x4){b_z[Th],  b_z[Th],  b_z[Th],  b_z[Th]};
        aHN[Th] = (f32x4){b_hn[Th], b_hn[Th], b_hn[Th], b_hn[Th]};
        aIN[Th] = (f32x4){b_in[Th], b_in[Th], b_in[Th], b_in[Th]};
      }
#pragma unroll
      for (int Th = 0; Th < 4; ++Th) {
        aR[Th]  = mmh(aR[Th],  A0, A1, Bh[Th]);
        aZ[Th]  = mmh(aZ[Th],  A0, A1, Bh[4 + Th]);
        aHN[Th] = mmh(aHN[Th], A0, A1, Bh[8 + Th]);
      }
      if (din1) {
#pragma unroll
        for (int Th = 0; Th < 4; ++Th)
#pragma unroll
          for (int q = 0; q < 4; ++q) {
            aR[Th][q]  += xcur[q] * w_r[Th];
            aZ[Th][q]  += xcur[q] * w_z[Th];
            aIN[Th][q] += xcur[q] * w_n[Th];
          }
        if (t + 1 < 512) {                      // prefetch next step's x
          const float* xp = P.xseq + (size_t)row_base * 512 + (t + 1);
#pragma unroll
          for (int q = 0; q < 4; ++q) xcur[q] = xp[(size_t)(4 * q16 + q) * 512];
        }
      } else {
#pragma unroll
        for (int Th = 0; Th < 4; ++Th) {
          aR[Th]  = mmx(aR[Th],  X0, X1, Bx[Th]);
          aZ[Th]  = mmx(aZ[Th],  X0, X1, Bx[4 + Th]);
          aIN[Th] = mmx(aIN[Th], X0, X1, Bx[8 + Th]);
        }
      }

      // ---- activations + state update + publish (parity t&1)
      unsigned short* wp = ring + (g * 2 + (t & 1)) * REG;
      float yp[4] = {0.f, 0.f, 0.f, 0.f};
#pragma unroll
      for (int Th = 0; Th < 4; ++Th)
#pragma unroll
        for (int q = 0; q < 4; ++q) {
          float r = __builtin_amdgcn_rcpf(1.f + __expf(-aR[Th][q]));
          float z = __builtin_amdgcn_rcpf(1.f + __expf(-aZ[Th][q]));
          float na = aIN[Th][q] + r * aHN[Th][q];
          float e2 = __expf(2.f * na);
          float n  = __builtin_fmaf(-2.f, __builtin_amdgcn_rcpf(e2 + 1.f), 1.f);
          float h  = n + z * (hreg[Th][q] - n);
          hreg[Th][q] = h;
          wp[woq[q] + 16 * Th] = f2h(h);
          if (yd) yp[q] = __builtin_fmaf(h, lwv[Th], yp[q]);
        }

      // ---- decoder: y_t = h2_t @ lin_w + lin_b (16-lane reduce over c16)
      if (yd) {
#pragma unroll
        for (int m = 1; m < 16; m <<= 1) {
#pragma unroll
          for (int q = 0; q < 4; ++q) yp[q] += __shfl_xor(yp[q], m, 64);
        }
        if (c16 == 0) {
#pragma unroll
          for (int q = 0; q < 4; ++q)
            P.y[(size_t)(row_base + 4 * q16 + q) * 512 + t] = yp[q] + lb;
        }
      }

      // ---- encoder: store final hidden state
      if (!IS_DEC && t == 511) {
#pragma unroll
        for (int Th = 0; Th < 4; ++Th)
#pragma unroll
          for (int q = 0; q < 4; ++q)
            P.hfin_wr[((size_t)g * 2048 + row_base + 4 * q16 + q) * 64 +
                      c16 + 16 * Th] = hreg[Th][q];
      }
    }
    wg_barrier();
  }
}

// ---------------------------------------------------------------------------
extern "C" void kernel_launch(void* const* d_in, const int* in_sizes, int n_in,
                              void* d_out, int out_size, void* d_ws, size_t ws_size,
                              hipStream_t stream) {
  (void)in_sizes; (void)n_in; (void)out_size; (void)ws_size;
  const float* inputs  = (const float*)d_in[0];
  const float* outputs = (const float*)d_in[1];

  unsigned short* frags = (unsigned short*)d_ws;            // 638976 B
  float* hfin = (float*)((char*)d_ws + 655360);             // 1.5 MB

  static const int ofs[6]  = {2, 6, 10, 14, 18, 22};  // enc0,enc1,enc2,c1,c2,c3
  static const int dins[6] = {1, 60, 60, 1, 60, 60};

  PrepArgs pa;
  for (int ci = 0; ci < 6; ++ci) {
    pa.w[ci * 2 + 0]   = (const float*)d_in[ofs[ci] + 0];  // wih
    pa.w[ci * 2 + 1]   = (const float*)d_in[ofs[ci] + 1];  // whh
    pa.din[ci * 2 + 0] = dins[ci];
    pa.din[ci * 2 + 1] = 60;
  }
  pa.w[12]   = (const float*)d_in[26];                     // lin_w
  pa.din[12] = 60;
  pa.out = frags;
  prep_frags<<<dim3(1248), dim3(256), 0, stream>>>(pa);

  PhaseArgs ea;
  ea.xseq = inputs; ea.frags = frags;
  for (int gg = 0; gg < 3; ++gg) {
    ea.cell[gg].bih     = (const float*)d_in[ofs[gg] + 2];
    ea.cell[gg].bhh     = (const float*)d_in[ofs[gg] + 3];
    ea.cell[gg].wih_vec = (const float*)d_in[ofs[gg] + 0];
  }
  ea.hfin_rd = hfin; ea.hfin_wr = hfin;
  ea.lin_w = (const float*)d_in[26];
  ea.lin_b = (const float*)d_in[27];
  ea.y = (float*)d_out;
  gru_phase<0><<<dim3(128), dim3(192), 0, stream>>>(ea);

  PhaseArgs da = ea;
  da.xseq = outputs;
  for (int gg = 0; gg < 3; ++gg) {
    da.cell[gg].bih     = (const float*)d_in[ofs[3 + gg] + 2];
    da.cell[gg].bhh     = (const float*)d_in[ofs[3 + gg] + 3];
    da.cell[gg].wih_vec = (const float*)d_in[ofs[3 + gg] + 0];
  }
  gru_phase<1><<<dim3(128), dim3(192), 0, stream>>>(da);
}